// Round 4
// baseline (729.163 us; speedup 1.0000x reference)
//
#include <hip/hip_runtime.h>
#include <hip/hip_bf16.h>

#define N_NODES 50000
#define N_EDGES 1600000
#define IN_H 256
#define NHEAD 4
#define EDGE_H 64
#define N_ET 8

// ---- ws layout (word offsets), total 16,566,528 words = 66.3 MB ----
// counts   int[50000]     @ 0          (zeroed)
// cursor   int[50000]     @ 50000      (zeroed)
// hlmax    u32[4]         @ 100000     (zeroed; enc_f32-encoded maxima)
// hrmax    u32[4]         @ 100004
// hemax    u32[4]         @ 100008
// flag     int[1]         @ 100012
// hl       f32[200000]    @ 100064
// hr       f32[200000]    @ 300064
// offsets  int[50001]     @ 500064
// he       f32[32]        @ 550112
// Wt       bf16[32768]    @ 550144    (16384 words)
// rec      f32[12800000]  @ 566528    (32B/edge: p0..3, s, e, pad, pad)
// h        bf16[6400000]  @ 13366528  (3200000 words)

typedef __attribute__((ext_vector_type(8))) short bf16x8v;
typedef __attribute__((ext_vector_type(4))) float f32x4;

__device__ __forceinline__ float ldT(const float* p) { return *p; }
__device__ __forceinline__ float ldT(const __hip_bfloat16* p) { return __bfloat162float(*p); }
__device__ __forceinline__ void stT(float* p, float v) { *p = v; }
__device__ __forceinline__ void stT(__hip_bfloat16* p, float v) { *p = __float2bfloat16(v); }

__device__ __forceinline__ short f2bs(float f) {
    __hip_bfloat16 b = __float2bfloat16(f);
    return (short)__builtin_bit_cast(unsigned short, b);
}
__device__ __forceinline__ float bs2f(short s) {
    return __uint_as_float(((unsigned)(unsigned short)s) << 16);
}

__device__ __forceinline__ unsigned enc_f32(float f) {
    unsigned u = __float_as_uint(f);
    return (u & 0x80000000u) ? ~u : (u | 0x80000000u);
}
__device__ __forceinline__ float dec_f32(unsigned u) {
    return __uint_as_float((u & 0x80000000u) ? (u & 0x7fffffffu) : ~u);
}
__device__ __forceinline__ float lrelu(float v) { return v > 0.f ? v : 0.2f * v; }

// edge-type projection: he[ty][head] + hemax (enc-encoded atomicMax)
template<typename T>
__device__ __forceinline__ void edge_proj_body(const T* __restrict__ emb,
        const T* __restrict__ We, const T* __restrict__ ae,
        float* __restrict__ h_e, unsigned* __restrict__ hemax) {
    int t = threadIdx.x;          // col 0..255, head = t>>6
    int lane = t & 63;
    float aev_ = ldT(ae + t);
    for (int ty = 0; ty < N_ET; ++ty) {
        float acc = 0.f;
        for (int k = 0; k < EDGE_H; ++k)
            acc += ldT(emb + ty * EDGE_H + k) * ldT(We + k * 256 + t);
        float v = aev_ * acc;
        for (int off = 32; off; off >>= 1) v += __shfl_xor(v, off);
        if (lane == 0) {
            h_e[ty * NHEAD + (t >> 6)] = v;
            atomicMax(&hemax[t >> 6], enc_f32(v));
        }
    }
}

// one block: dtype detect -> flag; W transpose->bf16 Wt; edge projection+hemax.
// (merges 3 tiny launches into 1)
__global__ __launch_bounds__(256) void k_setup(
        const unsigned* __restrict__ xw, const void* __restrict__ Wv,
        const void* __restrict__ emb, const void* __restrict__ We,
        const void* __restrict__ ae,
        __hip_bfloat16* __restrict__ Wt, float* __restrict__ h_e,
        unsigned* __restrict__ hemax, int* __restrict__ flag) {
    __shared__ int sflag;
    int t = threadIdx.x;
    // phase 1: dtype detect (fp32 N(0,1) words have exp-field in [64,160])
    if (t < 64) {
        int cnt = 0;
        for (int i = t; i < 1024; i += 64) {
            unsigned e = (xw[i] >> 23) & 255u;
            if (e >= 64u && e <= 160u) cnt++;
        }
        for (int off = 32; off; off >>= 1) cnt += __shfl_xor(cnt, off);
        if (t == 0) { sflag = (cnt > 512) ? 1 : 0; *flag = sflag; }
    }
    __syncthreads();
    bool f32 = (sflag != 0);
    // phase 2: W[256][128] -> Wt[128][256] bf16 (B^T layout, contiguous along K)
    for (int i = t; i < 128 * 256; i += 256) {
        int c = i >> 8, k = i & 255;
        float v = f32 ? ((const float*)Wv)[k * 128 + c]
                      : __bfloat162float(((const __hip_bfloat16*)Wv)[k * 128 + c]);
        Wt[i] = __float2bfloat16(v);
    }
    // phase 3: edge projection + hemax
    if (f32) edge_proj_body<float>((const float*)emb, (const float*)We,
                                   (const float*)ae, h_e, hemax);
    else     edge_proj_body<__hip_bfloat16>((const __hip_bfloat16*)emb,
                                            (const __hip_bfloat16*)We,
                                            (const __hip_bfloat16*)ae, h_e, hemax);
}

// h = x @ W via mfma_f32_16x16x32_bf16.
// 4 waves/block = 2 row-groups x 2 col-halves. Wave: 16 rows x 64 cols
// (4 t-tiles), 12500 waves (~8/SIMD). Prologue: folded edge-count atomics
// (fire-and-forget, hide under MFMA). Epilogue: hl/hr from in-register h
// (no k_hlr) + per-head hl/hr maxima (4 atomicMax/wave, no k_aux).
template<typename T>
__device__ __forceinline__ void proj_body(const T* __restrict__ x,
        const __hip_bfloat16* __restrict__ Wt, __hip_bfloat16* __restrict__ h,
        float* __restrict__ hl, float* __restrict__ hr,
        const T* __restrict__ al, const T* __restrict__ ar,
        unsigned* __restrict__ hlmax, unsigned* __restrict__ hrmax) {
    int wid = threadIdx.x >> 6, lane = threadIdx.x & 63;
    int rg = blockIdx.x * 2 + (wid >> 1);
    if (rg >= 3125) return;                 // no barriers below: safe early-exit
    int toff = (wid & 1) * 4;               // col-half: t-tiles toff..toff+3
    int r0 = rg * 16;
    int r = lane & 15;
    int kb = (lane >> 4) * 8;
    const T* xrow = x + (size_t)(r0 + r) * IN_H;
    f32x4 z = {0.f, 0.f, 0.f, 0.f};
    f32x4 acc[4];
#pragma unroll
    for (int t = 0; t < 4; ++t) acc[t] = z;
#pragma unroll
    for (int kk = 0; kk < 8; ++kk) {
        int k0 = kk * 32 + kb;
        bf16x8v a;
        if constexpr (sizeof(T) == 4) {
            float4 lo = *(const float4*)(xrow + k0);
            float4 hi = *(const float4*)(xrow + k0 + 4);
            a[0] = f2bs(lo.x); a[1] = f2bs(lo.y); a[2] = f2bs(lo.z); a[3] = f2bs(lo.w);
            a[4] = f2bs(hi.x); a[5] = f2bs(hi.y); a[6] = f2bs(hi.z); a[7] = f2bs(hi.w);
        } else {
            a = *(const bf16x8v*)(xrow + k0);
        }
#pragma unroll
        for (int t = 0; t < 4; ++t) {
            bf16x8v b = *(const bf16x8v*)(Wt + ((toff + t) * 16 + r) * 256 + k0);
            acc[t] = __builtin_amdgcn_mfma_f32_16x16x32_bf16(a, b, acc[t], 0, 0, 0);
        }
    }
    // epilogue: store h, accumulate hl/hr partials
    float alc[4], arc[4];
#pragma unroll
    for (int t = 0; t < 4; ++t) {
        alc[t] = ldT(al + (toff + t) * 16 + r);
        arc[t] = ldT(ar + (toff + t) * 16 + r);
    }
    int ob = (lane >> 4) * 4;               // this quarter's row offset
    float pl[2][4] = {{0,0,0,0},{0,0,0,0}}, pr[2][4] = {{0,0,0,0},{0,0,0,0}};
#pragma unroll
    for (int t = 0; t < 4; ++t) {
        int col = (toff + t) * 16 + r;
#pragma unroll
        for (int g = 0; g < 4; ++g) {
            float v = acc[t][g];
            if (v != v) v = 0.f;            // reference: where(isnan(h), 0)
            h[(size_t)(r0 + ob + g) * 128 + col] = __float2bfloat16(v);
            pl[t >> 1][g] += alc[t] * v;
            pr[t >> 1][g] += arc[t] * v;
        }
    }
    const float NEG = -3.4e38f;
    float mxl[2] = {NEG, NEG}, mxr[2] = {NEG, NEG};
#pragma unroll
    for (int hh = 0; hh < 2; ++hh)
#pragma unroll
        for (int g = 0; g < 4; ++g) {
            float vl = pl[hh][g], vr = pr[hh][g];
#pragma unroll
            for (int off = 8; off; off >>= 1) {
                vl += __shfl_xor(vl, off);
                vr += __shfl_xor(vr, off);
            }
            mxl[hh] = fmaxf(mxl[hh], vl);   // butterfly: all lanes hold the sum
            mxr[hh] = fmaxf(mxr[hh], vr);
            if (r == 0) {
                int node = r0 + ob + g;
                hl[node * 4 + (toff >> 1) + hh] = vl;
                hr[node * 4 + (toff >> 1) + hh] = vr;
            }
        }
    // wave-level per-head maxima (over this wave's 16 nodes)
#pragma unroll
    for (int hh = 0; hh < 2; ++hh) {
        float a = mxl[hh], b = mxr[hh];
        a = fmaxf(a, __shfl_xor(a, 16)); a = fmaxf(a, __shfl_xor(a, 32));
        b = fmaxf(b, __shfl_xor(b, 16)); b = fmaxf(b, __shfl_xor(b, 32));
        if (lane == 0) {
            atomicMax(&hlmax[(toff >> 1) + hh], enc_f32(a));
            atomicMax(&hrmax[(toff >> 1) + hh], enc_f32(b));
        }
    }
}

__global__ __launch_bounds__(256) void k_proj(const void* __restrict__ xv,
        const __hip_bfloat16* __restrict__ Wt, __hip_bfloat16* __restrict__ h,
        float* __restrict__ hl, float* __restrict__ hr,
        const void* __restrict__ al, const void* __restrict__ ar,
        const int* __restrict__ edge, int* __restrict__ counts,
        unsigned* __restrict__ hlmax, unsigned* __restrict__ hrmax,
        const int* __restrict__ flag) {
    // folded k_count: fire-and-forget atomics retire under the MFMA body
    {
        int base = blockIdx.x * 1024;
        int lim = min(base + 1024, N_EDGES);
        for (int i = base + threadIdx.x; i < lim; i += 256)
            atomicAdd(&counts[edge[N_EDGES + i]], 1);
    }
    if (*flag) proj_body<float>((const float*)xv, Wt, h, hl, hr,
                                (const float*)al, (const float*)ar, hlmax, hrmax);
    else       proj_body<__hip_bfloat16>((const __hip_bfloat16*)xv, Wt, h, hl, hr,
                                         (const __hip_bfloat16*)al,
                                         (const __hip_bfloat16*)ar, hlmax, hrmax);
}

__global__ __launch_bounds__(256) void k_scan(
        const int* __restrict__ counts, int* __restrict__ offsets) {
    __shared__ int psum[256];
    int t = threadIdx.x;
    const int CHUNK = 196;
    int start = t * CHUNK;
    int end = min(start + CHUNK, N_NODES);
    int s = 0;
    for (int i = start; i < end; ++i) s += counts[i];
    psum[t] = s;
    __syncthreads();
    for (int off = 1; off < 256; off <<= 1) {
        int v = (t >= off) ? psum[t - off] : 0;
        __syncthreads();
        psum[t] += v;
        __syncthreads();
    }
    int run = (t == 0) ? 0 : psum[t - 1];
    for (int i = start; i < end; ++i) { offsets[i] = run; run += counts[i]; }
    if (t == 255) offsets[N_NODES] = run;
}

// CSR build: per edge one 32B record {p0..p3, s, e, pad, pad}, where
// p_h = exp(score_h - M_h) with M_h = lrelu(max hl_h + max hr_h + max he_h)
// (monotone lrelu => valid upper bound; softmax is shift-invariant per head,
// so the result is mathematically identical to the reference's global max).
__global__ __launch_bounds__(256) void k_build(
        const int* __restrict__ edge, const int* __restrict__ offsets,
        int* __restrict__ cursor,
        const float* __restrict__ hl, const float* __restrict__ hr,
        const float* __restrict__ he,
        const unsigned* __restrict__ hlmax, const unsigned* __restrict__ hrmax,
        const unsigned* __restrict__ hemax,
        float* __restrict__ rec) {
    float M0 = lrelu(dec_f32(hlmax[0]) + dec_f32(hrmax[0]) + dec_f32(hemax[0]));
    float M1 = lrelu(dec_f32(hlmax[1]) + dec_f32(hrmax[1]) + dec_f32(hemax[1]));
    float M2 = lrelu(dec_f32(hlmax[2]) + dec_f32(hrmax[2]) + dec_f32(hemax[2]));
    float M3 = lrelu(dec_f32(hlmax[3]) + dec_f32(hrmax[3]) + dec_f32(hemax[3]));
    int e = blockIdx.x * 256 + threadIdx.x;   // 6250*256 == N_EDGES exactly
    int s = edge[e], t = edge[N_EDGES + e], ty = edge[2 * N_EDGES + e];
    int pos = offsets[t] + atomicAdd(&cursor[t], 1);
    float4 a = *(const float4*)(hl + s * 4);
    float4 b = *(const float4*)(hr + t * 4);
    float4 c = *(const float4*)(he + ty * 4);
    float4 p;
    p.x = __expf(lrelu(a.x + b.x + c.x) - M0);
    p.y = __expf(lrelu(a.y + b.y + c.y) - M1);
    p.z = __expf(lrelu(a.z + b.z + c.z) - M2);
    p.w = __expf(lrelu(a.w + b.w + c.w) - M3);
    float4 se;
    se.x = __int_as_float(s); se.y = __int_as_float(e); se.z = 0.f; se.w = 0.f;
    float* rp = rec + (size_t)pos * 8;
    *(float4*)rp = p;
    *(float4*)(rp + 4) = se;
}

// one wave per node. pass1: lane-parallel denom (pure sums, no exp).
// pass2: 4 edges/iter — quarter-wave owns an edge, 16 lanes own 8 dims each
// (16B h load), cross-quarter shfl reduce at end. Zero transcendentals.
template<typename OUTT>
__device__ __forceinline__ void agg_body(
        const float* __restrict__ rec, const int* __restrict__ offsets,
        const __hip_bfloat16* __restrict__ h, OUTT* __restrict__ out) {
    int node = (blockIdx.x << 2) + (threadIdx.x >> 6);
    if (node >= N_NODES) return;
    int lane = threadIdx.x & 63;
    int beg = offsets[node], end = offsets[node + 1];

    // pass 1: denominators
    float d0 = 0.f, d1 = 0.f, d2 = 0.f, d3 = 0.f;
    for (int j = beg + lane; j < end; j += 64) {
        float4 p = *(const float4*)(rec + (size_t)j * 8);
        d0 += p.x; d1 += p.y; d2 += p.z; d3 += p.w;
    }
#pragma unroll
    for (int off = 32; off; off >>= 1) {
        d0 += __shfl_xor(d0, off); d1 += __shfl_xor(d1, off);
        d2 += __shfl_xor(d2, off); d3 += __shfl_xor(d3, off);
    }
    float inv0 = 1.f / (d0 + 1e-16f), inv1 = 1.f / (d1 + 1e-16f);
    float inv2 = 1.f / (d2 + 1e-16f), inv3 = 1.f / (d3 + 1e-16f);

    int sub = lane >> 4;          // edge slot within group of 4
    int l16 = lane & 15;          // dim group: flat dims l16*8 .. +8
    int hd  = l16 >> 2;           // head of my dims
    float invd = hd == 0 ? inv0 : hd == 1 ? inv1 : hd == 2 ? inv2 : inv3;
    float inva = l16 == 0 ? inv0 : l16 == 1 ? inv1 : l16 == 2 ? inv2 : inv3;
    OUTT* attn_out = out + (size_t)N_NODES * 128;

    float acc[8] = {0.f, 0.f, 0.f, 0.f, 0.f, 0.f, 0.f, 0.f};
    for (int jg = beg; jg < end; jg += 4) {
        int j = jg + sub;
        bool valid = j < end;
        int jc = valid ? j : end - 1;
        const float* rp = rec + (size_t)jc * 8;
        float4 p = *(const float4*)rp;
        int2 se = *(const int2*)(rp + 4);
        int s = se.x;
        if (valid && l16 < 4) {    // attn output: lanes 0..3 of each quarter
            float ph = l16 == 0 ? p.x : l16 == 1 ? p.y : l16 == 2 ? p.z : p.w;
            stT(&attn_out[(size_t)se.y * 4 + l16], ph * inva);
        }
        float phd = hd == 0 ? p.x : hd == 1 ? p.y : hd == 2 ? p.z : p.w;
        float w = valid ? phd * invd : 0.f;
        bf16x8v hv = *(const bf16x8v*)(h + (size_t)s * 128 + l16 * 8);
#pragma unroll
        for (int i = 0; i < 8; ++i) acc[i] += bs2f(hv[i]) * w;
    }
#pragma unroll
    for (int i = 0; i < 8; ++i) {
        acc[i] += __shfl_xor(acc[i], 16);
        acc[i] += __shfl_xor(acc[i], 32);
    }
    if (sub == 0) {
#pragma unroll
        for (int i = 0; i < 8; ++i)
            stT(&out[(size_t)node * 128 + l16 * 8 + i], acc[i]);
    }
}

__global__ __launch_bounds__(256) void k_agg(
        const float* __restrict__ rec, const int* __restrict__ offsets,
        const __hip_bfloat16* __restrict__ h,
        void* __restrict__ outv, const int* __restrict__ flag) {
    if (*flag) agg_body<float>(rec, offsets, h, (float*)outv);
    else       agg_body<__hip_bfloat16>(rec, offsets, h, (__hip_bfloat16*)outv);
}

extern "C" void kernel_launch(void* const* d_in, const int* in_sizes, int n_in,
                              void* d_out, int out_size, void* d_ws, size_t ws_size,
                              hipStream_t stream) {
    const int* edge = (const int*)d_in[0];
    const void* x   = d_in[1];
    const void* emb = d_in[2];
    const void* W   = d_in[3];
    const void* We  = d_in[4];
    const void* al  = d_in[5];
    const void* ar  = d_in[6];
    const void* ae  = d_in[7];

    float* ws = (float*)d_ws;
    int* counts     = (int*)ws;                        // 50000
    int* cursor     = counts + 50000;                  // 50000
    unsigned* hlmax = (unsigned*)(counts + 100000);    // 4
    unsigned* hrmax = hlmax + 4;                       // 4
    unsigned* hemax = hlmax + 8;                       // 4
    int* flag       = counts + 100012;                 // 1
    float* hl       = ws + 100064;                     // 200000
    float* hr       = ws + 300064;                     // 200000
    int* offsets    = (int*)ws + 500064;               // 50001
    float* he       = ws + 550112;                     // 32
    __hip_bfloat16* Wt = (__hip_bfloat16*)(ws + 550144);   // 32768 bf16
    float* rec      = ws + 566528;                     // 12,800,000 (32B-aligned)
    __hip_bfloat16* h = (__hip_bfloat16*)(ws + 13366528);  // 6,400,000 bf16
    // total 16,566,528 words = 66.3 MB

    hipMemsetAsync(ws, 0, (size_t)100064 * 4, stream); // counts+cursor+maxima+flag

    k_setup<<<1, 256, 0, stream>>>((const unsigned*)x, W, emb, We, ae,
                                   Wt, he, hemax, flag);
    k_proj<<<1563, 256, 0, stream>>>(x, Wt, h, hl, hr, al, ar,
                                     edge, counts, hlmax, hrmax, flag);
    k_scan<<<1, 256, 0, stream>>>(counts, offsets);
    k_build<<<6250, 256, 0, stream>>>(edge, offsets, cursor, hl, hr, he,
                                      hlmax, hrmax, hemax, rec);
    k_agg<<<12500, 256, 0, stream>>>(rec, offsets, h, d_out, flag);
}

// Round 6
// 456.201 us; speedup vs baseline: 1.5983x; 1.5983x over previous
//
#include <hip/hip_runtime.h>
#include <hip/hip_bf16.h>

#define N_NODES 50000
#define N_EDGES 1600000
#define IN_H 256
#define NHEAD 4
#define EDGE_H 64
#define N_ET 8

// ---- ws layout (word offsets), total 16,566,528 words = 66.3 MB ----
// counts   int[50000]     @ 0          (zeroed)
// cursor   int[50000]     @ 50000      (zeroed)
// hlmax    u32[4]         @ 100000     (zeroed; enc_f32-encoded maxima)
// hrmax    u32[4]         @ 100004
// hemax    u32[4]         @ 100008
// flag     int[1]         @ 100012
// hl       f32[200000]    @ 100064
// hr       f32[200000]    @ 300064
// offsets  int[50001]     @ 500064
// he       f32[32]        @ 550112
// Wt       bf16[32768]    @ 550144    (16384 words)
// rec      f32[12800000]  @ 566528    (32B/edge: p0..3, s, e, pad, pad)
// h        bf16[6400000]  @ 13366528  (3200000 words)

typedef __attribute__((ext_vector_type(8))) short bf16x8v;
typedef __attribute__((ext_vector_type(4))) float f32x4;

__device__ __forceinline__ float ldT(const float* p) { return *p; }
__device__ __forceinline__ float ldT(const __hip_bfloat16* p) { return __bfloat162float(*p); }
__device__ __forceinline__ void stT(float* p, float v) { *p = v; }
__device__ __forceinline__ void stT(__hip_bfloat16* p, float v) { *p = __float2bfloat16(v); }

__device__ __forceinline__ short f2bs(float f) {
    __hip_bfloat16 b = __float2bfloat16(f);
    return (short)__builtin_bit_cast(unsigned short, b);
}
__device__ __forceinline__ float bs2f(short s) {
    return __uint_as_float(((unsigned)(unsigned short)s) << 16);
}

__device__ __forceinline__ unsigned enc_f32(float f) {
    unsigned u = __float_as_uint(f);
    return (u & 0x80000000u) ? ~u : (u | 0x80000000u);
}
__device__ __forceinline__ float dec_f32(unsigned u) {
    return __uint_as_float((u & 0x80000000u) ? (u & 0x7fffffffu) : ~u);
}
__device__ __forceinline__ float lrelu(float v) { return v > 0.f ? v : 0.2f * v; }

// dtype detector: fp32 N(0,1) words have exp-field in [64,160]; bf16-packed
// words don't. DEVICE-side sniffing is the only proven dispatch here:
// in_sizes[] are ELEMENT counts (R5 post-mortem), so host can't tell dtypes.
__global__ void k_detect(const unsigned* __restrict__ xw, int* __restrict__ flag) {
    int lane = threadIdx.x;   // 64 threads
    int cnt = 0;
    for (int i = lane; i < 1024; i += 64) {
        unsigned e = (xw[i] >> 23) & 255u;
        if (e >= 64u && e <= 160u) cnt++;
    }
    for (int off = 32; off; off >>= 1) cnt += __shfl_xor(cnt, off);
    if (lane == 0) *flag = (cnt > 512) ? 1 : 0;   // 1 = fp32, 0 = bf16
}

// b0: W[256][128] -> Wt[128][256] bf16 (B^T layout for MFMA).
// b1..8: edge-type projection for type (b-1): he[ty][head] + hemax.
template<typename T, int EXPECT>
__global__ __launch_bounds__(256) void k_setup(
        const void* __restrict__ Wv, const void* __restrict__ embv,
        const void* __restrict__ Wev, const void* __restrict__ aev,
        __hip_bfloat16* __restrict__ Wt, float* __restrict__ h_e,
        unsigned* __restrict__ hemax, const int* __restrict__ flag) {
    if (*flag != EXPECT) return;
    const T* W   = (const T*)Wv;
    const T* emb = (const T*)embv;
    const T* We  = (const T*)Wev;
    const T* ae  = (const T*)aev;
    if (blockIdx.x == 0) {
        for (int i = threadIdx.x; i < 128 * 256; i += 256) {
            int c = i >> 8, k = i & 255;
            Wt[i] = __float2bfloat16(ldT(W + k * 128 + c));
        }
        return;
    }
    int ty = blockIdx.x - 1;
    int t = threadIdx.x, lane = t & 63;
    float acc = 0.f;
    for (int k = 0; k < EDGE_H; ++k)
        acc += ldT(emb + ty * EDGE_H + k) * ldT(We + k * 256 + t);
    float v = ldT(ae + t) * acc;
    for (int off = 32; off; off >>= 1) v += __shfl_xor(v, off);
    if (lane == 0) {
        h_e[ty * NHEAD + (t >> 6)] = v;
        atomicMax(&hemax[t >> 6], enc_f32(v));
    }
}

// h = x @ W via mfma_f32_16x16x32_bf16.
// 4 waves/block = 2 row-groups x 2 col-halves. Wave: 16 rows x 64 cols
// (4 t-tiles), 12500 waves (~8/SIMD). Epilogue computes hl/hr from the
// in-register h (quarter-lane butterfly; col-half waves own disjoint heads
// -> plain stores). NO per-wave maxima atomics (R4: 100K atomicMax to one
// line serialized, +250us).
template<typename T, int EXPECT>
__global__ __launch_bounds__(256) void k_proj(const void* __restrict__ xv,
        const __hip_bfloat16* __restrict__ Wt, __hip_bfloat16* __restrict__ h,
        float* __restrict__ hl, float* __restrict__ hr,
        const void* __restrict__ alv, const void* __restrict__ arv,
        const int* __restrict__ flag) {
    if (*flag != EXPECT) return;
    const T* x  = (const T*)xv;
    const T* al = (const T*)alv;
    const T* ar = (const T*)arv;
    int wid = threadIdx.x >> 6, lane = threadIdx.x & 63;
    int rg = blockIdx.x * 2 + (wid >> 1);
    if (rg >= 3125) return;                 // no barriers below: safe early-exit
    int toff = (wid & 1) * 4;               // col-half: t-tiles toff..toff+3
    int r0 = rg * 16;
    int r = lane & 15;
    int kb = (lane >> 4) * 8;
    const T* xrow = x + (size_t)(r0 + r) * IN_H;
    f32x4 z = {0.f, 0.f, 0.f, 0.f};
    f32x4 acc[4];
#pragma unroll
    for (int t = 0; t < 4; ++t) acc[t] = z;
#pragma unroll
    for (int kk = 0; kk < 8; ++kk) {
        int k0 = kk * 32 + kb;
        bf16x8v a;
        if constexpr (sizeof(T) == 4) {
            float4 lo = *(const float4*)(xrow + k0);
            float4 hi = *(const float4*)(xrow + k0 + 4);
            a[0] = f2bs(lo.x); a[1] = f2bs(lo.y); a[2] = f2bs(lo.z); a[3] = f2bs(lo.w);
            a[4] = f2bs(hi.x); a[5] = f2bs(hi.y); a[6] = f2bs(hi.z); a[7] = f2bs(hi.w);
        } else {
            a = *(const bf16x8v*)(xrow + k0);
        }
#pragma unroll
        for (int t = 0; t < 4; ++t) {
            bf16x8v b = *(const bf16x8v*)(Wt + ((toff + t) * 16 + r) * 256 + k0);
            acc[t] = __builtin_amdgcn_mfma_f32_16x16x32_bf16(a, b, acc[t], 0, 0, 0);
        }
    }
    // epilogue: store h, accumulate hl/hr partials
    float alc[4], arc[4];
#pragma unroll
    for (int t = 0; t < 4; ++t) {
        alc[t] = ldT(al + (toff + t) * 16 + r);
        arc[t] = ldT(ar + (toff + t) * 16 + r);
    }
    int ob = (lane >> 4) * 4;               // this quarter's row offset
    float pl[2][4] = {{0,0,0,0},{0,0,0,0}}, pr[2][4] = {{0,0,0,0},{0,0,0,0}};
#pragma unroll
    for (int t = 0; t < 4; ++t) {
        int col = (toff + t) * 16 + r;
#pragma unroll
        for (int g = 0; g < 4; ++g) {
            float v = acc[t][g];
            if (v != v) v = 0.f;            // reference: where(isnan(h), 0)
            h[(size_t)(r0 + ob + g) * 128 + col] = __float2bfloat16(v);
            pl[t >> 1][g] += alc[t] * v;
            pr[t >> 1][g] += arc[t] * v;
        }
    }
#pragma unroll
    for (int hh = 0; hh < 2; ++hh)
#pragma unroll
        for (int g = 0; g < 4; ++g) {
            float vl = pl[hh][g], vr = pr[hh][g];
#pragma unroll
            for (int off = 8; off; off >>= 1) {
                vl += __shfl_xor(vl, off);
                vr += __shfl_xor(vr, off);
            }
            if (r == 0) {
                int node = r0 + ob + g;
                hl[node * 4 + (toff >> 1) + hh] = vl;
                hr[node * 4 + (toff >> 1) + hh] = vr;
            }
        }
}

// per-target edge counts (1 atomic/thread, 6250*256 == N_EDGES) + folded
// hl/hr per-head maxima on the first 128 blocks (2048 total atomicMax —
// the measured-safe volume from R3's k_aux).
__global__ __launch_bounds__(256) void k_countaux(
        const int* __restrict__ edge, int* __restrict__ counts,
        const float* __restrict__ hl, const float* __restrict__ hr,
        unsigned* __restrict__ hlmax, unsigned* __restrict__ hrmax) {
    int e = blockIdx.x * 256 + threadIdx.x;
    atomicAdd(&counts[edge[N_EDGES + e]], 1);
    if (blockIdx.x >= 128) return;
    const float NEG = -3.4e38f;
    float4 ml = {NEG, NEG, NEG, NEG}, mr = {NEG, NEG, NEG, NEG};
    for (int n = blockIdx.x * 256 + threadIdx.x; n < N_NODES; n += 128 * 256) {
        float4 a = *(const float4*)(hl + n * 4);
        float4 b = *(const float4*)(hr + n * 4);
        ml.x = fmaxf(ml.x, a.x); ml.y = fmaxf(ml.y, a.y);
        ml.z = fmaxf(ml.z, a.z); ml.w = fmaxf(ml.w, a.w);
        mr.x = fmaxf(mr.x, b.x); mr.y = fmaxf(mr.y, b.y);
        mr.z = fmaxf(mr.z, b.z); mr.w = fmaxf(mr.w, b.w);
    }
#pragma unroll
    for (int off = 32; off; off >>= 1) {
        ml.x = fmaxf(ml.x, __shfl_xor(ml.x, off));
        ml.y = fmaxf(ml.y, __shfl_xor(ml.y, off));
        ml.z = fmaxf(ml.z, __shfl_xor(ml.z, off));
        ml.w = fmaxf(ml.w, __shfl_xor(ml.w, off));
        mr.x = fmaxf(mr.x, __shfl_xor(mr.x, off));
        mr.y = fmaxf(mr.y, __shfl_xor(mr.y, off));
        mr.z = fmaxf(mr.z, __shfl_xor(mr.z, off));
        mr.w = fmaxf(mr.w, __shfl_xor(mr.w, off));
    }
    if ((threadIdx.x & 63) == 0) {
        atomicMax(&hlmax[0], enc_f32(ml.x)); atomicMax(&hlmax[1], enc_f32(ml.y));
        atomicMax(&hlmax[2], enc_f32(ml.z)); atomicMax(&hlmax[3], enc_f32(ml.w));
        atomicMax(&hrmax[0], enc_f32(mr.x)); atomicMax(&hrmax[1], enc_f32(mr.y));
        atomicMax(&hrmax[2], enc_f32(mr.z)); atomicMax(&hrmax[3], enc_f32(mr.w));
    }
}

// exclusive scan of counts -> offsets, int4-vectorized both passes.
__global__ __launch_bounds__(256) void k_scan(
        const int* __restrict__ counts, int* __restrict__ offsets) {
    __shared__ int psum[256];
    int t = threadIdx.x;
    const int CHUNK = 196;                  // 49 int4, 16B-aligned per thread
    int start = t * CHUNK;
    int end = min(start + CHUNK, N_NODES);
    int s = 0;
    for (int i = start; i < end; i += 4) {
        int4 c = *(const int4*)(counts + i);
        s += c.x + c.y + c.z + c.w;
    }
    psum[t] = s;
    __syncthreads();
    for (int off = 1; off < 256; off <<= 1) {
        int v = (t >= off) ? psum[t - off] : 0;
        __syncthreads();
        psum[t] += v;
        __syncthreads();
    }
    int run = (t == 0) ? 0 : psum[t - 1];
    for (int i = start; i < end; i += 4) {
        int4 c = *(const int4*)(counts + i);
        int4 o;
        o.x = run; o.y = run + c.x; o.z = o.y + c.y; o.w = o.z + c.z;
        *(int4*)(offsets + i) = o;
        run = o.w + c.w;
    }
    if (t == 255) offsets[N_NODES] = run;
}

// CSR build: per edge one 32B record {p0..p3, s, e, pad, pad}, where
// p_h = exp(score_h - M_h) with M_h = lrelu(max hl_h + max hr_h + max he_h)
// (monotone lrelu => valid upper bound; per-head softmax shift-invariance
// makes this mathematically identical to the reference's global max).
__global__ __launch_bounds__(256) void k_build(
        const int* __restrict__ edge, const int* __restrict__ offsets,
        int* __restrict__ cursor,
        const float* __restrict__ hl, const float* __restrict__ hr,
        const float* __restrict__ he,
        const unsigned* __restrict__ hlmax, const unsigned* __restrict__ hrmax,
        const unsigned* __restrict__ hemax,
        float* __restrict__ rec) {
    float M0 = lrelu(dec_f32(hlmax[0]) + dec_f32(hrmax[0]) + dec_f32(hemax[0]));
    float M1 = lrelu(dec_f32(hlmax[1]) + dec_f32(hrmax[1]) + dec_f32(hemax[1]));
    float M2 = lrelu(dec_f32(hlmax[2]) + dec_f32(hrmax[2]) + dec_f32(hemax[2]));
    float M3 = lrelu(dec_f32(hlmax[3]) + dec_f32(hrmax[3]) + dec_f32(hemax[3]));
    int e = blockIdx.x * 256 + threadIdx.x;   // 6250*256 == N_EDGES exactly
    int s = edge[e], t = edge[N_EDGES + e], ty = edge[2 * N_EDGES + e];
    int pos = offsets[t] + atomicAdd(&cursor[t], 1);
    float4 a = *(const float4*)(hl + s * 4);
    float4 b = *(const float4*)(hr + t * 4);
    float4 c = *(const float4*)(he + ty * 4);
    float4 p;
    p.x = __expf(lrelu(a.x + b.x + c.x) - M0);
    p.y = __expf(lrelu(a.y + b.y + c.y) - M1);
    p.z = __expf(lrelu(a.z + b.z + c.z) - M2);
    p.w = __expf(lrelu(a.w + b.w + c.w) - M3);
    float4 se;
    se.x = __int_as_float(s); se.y = __int_as_float(e); se.z = 0.f; se.w = 0.f;
    float* rp = rec + (size_t)pos * 8;
    *(float4*)rp = p;
    *(float4*)(rp + 4) = se;
}

// one wave per node. pass1: lane-parallel denom (pure sums, no exp).
// pass2: 4 edges/iter — quarter-wave owns an edge, 16 lanes own 8 dims each
// (16B h load), cross-quarter shfl reduce at end. Zero transcendentals.
template<typename OUTT, int EXPECT>
__global__ __launch_bounds__(256) void k_agg(
        const float* __restrict__ rec, const int* __restrict__ offsets,
        const __hip_bfloat16* __restrict__ h, void* __restrict__ outv,
        const int* __restrict__ flag) {
    if (*flag != EXPECT) return;
    OUTT* out = (OUTT*)outv;
    int node = (blockIdx.x << 2) + (threadIdx.x >> 6);
    if (node >= N_NODES) return;
    int lane = threadIdx.x & 63;
    int beg = offsets[node], end = offsets[node + 1];

    // pass 1: denominators
    float d0 = 0.f, d1 = 0.f, d2 = 0.f, d3 = 0.f;
    for (int j = beg + lane; j < end; j += 64) {
        float4 p = *(const float4*)(rec + (size_t)j * 8);
        d0 += p.x; d1 += p.y; d2 += p.z; d3 += p.w;
    }
#pragma unroll
    for (int off = 32; off; off >>= 1) {
        d0 += __shfl_xor(d0, off); d1 += __shfl_xor(d1, off);
        d2 += __shfl_xor(d2, off); d3 += __shfl_xor(d3, off);
    }
    float inv0 = 1.f / (d0 + 1e-16f), inv1 = 1.f / (d1 + 1e-16f);
    float inv2 = 1.f / (d2 + 1e-16f), inv3 = 1.f / (d3 + 1e-16f);

    int sub = lane >> 4;          // edge slot within group of 4
    int l16 = lane & 15;          // dim group: flat dims l16*8 .. +8
    int hd  = l16 >> 2;           // head of my dims
    float invd = hd == 0 ? inv0 : hd == 1 ? inv1 : hd == 2 ? inv2 : inv3;
    float inva = l16 == 0 ? inv0 : l16 == 1 ? inv1 : l16 == 2 ? inv2 : inv3;
    OUTT* attn_out = out + (size_t)N_NODES * 128;

    float acc[8] = {0.f, 0.f, 0.f, 0.f, 0.f, 0.f, 0.f, 0.f};
    for (int jg = beg; jg < end; jg += 4) {
        int j = jg + sub;
        bool valid = j < end;
        int jc = valid ? j : end - 1;
        const float* rp = rec + (size_t)jc * 8;
        float4 p = *(const float4*)rp;
        int2 se = *(const int2*)(rp + 4);
        int s = se.x;
        if (valid && l16 < 4) {    // attn output: lanes 0..3 of each quarter
            float ph = l16 == 0 ? p.x : l16 == 1 ? p.y : l16 == 2 ? p.z : p.w;
            stT(&attn_out[(size_t)se.y * 4 + l16], ph * inva);
        }
        float phd = hd == 0 ? p.x : hd == 1 ? p.y : hd == 2 ? p.z : p.w;
        float w = valid ? phd * invd : 0.f;
        bf16x8v hv = *(const bf16x8v*)(h + (size_t)s * 128 + l16 * 8);
#pragma unroll
        for (int i = 0; i < 8; ++i) acc[i] += bs2f(hv[i]) * w;
    }
#pragma unroll
    for (int i = 0; i < 8; ++i) {
        acc[i] += __shfl_xor(acc[i], 16);
        acc[i] += __shfl_xor(acc[i], 32);
    }
    if (sub == 0) {
#pragma unroll
        for (int i = 0; i < 8; ++i)
            stT(&out[(size_t)node * 128 + l16 * 8 + i], acc[i]);
    }
}

extern "C" void kernel_launch(void* const* d_in, const int* in_sizes, int n_in,
                              void* d_out, int out_size, void* d_ws, size_t ws_size,
                              hipStream_t stream) {
    const int* edge = (const int*)d_in[0];
    const void* x   = d_in[1];
    const void* emb = d_in[2];
    const void* W   = d_in[3];
    const void* We  = d_in[4];
    const void* al  = d_in[5];
    const void* ar  = d_in[6];
    const void* ae  = d_in[7];

    float* ws = (float*)d_ws;
    int* counts     = (int*)ws;                        // 50000
    int* cursor     = counts + 50000;                  // 50000
    unsigned* hlmax = (unsigned*)(counts + 100000);    // 4
    unsigned* hrmax = hlmax + 4;                       // 4
    unsigned* hemax = hlmax + 8;                       // 4
    int* flag       = counts + 100012;                 // 1
    float* hl       = ws + 100064;                     // 200000
    float* hr       = ws + 300064;                     // 200000
    int* offsets    = (int*)ws + 500064;               // 50001
    float* he       = ws + 550112;                     // 32
    __hip_bfloat16* Wt = (__hip_bfloat16*)(ws + 550144);   // 32768 bf16
    float* rec      = ws + 566528;                     // 12,800,000 (32B-aligned)
    __hip_bfloat16* h = (__hip_bfloat16*)(ws + 13366528);  // 6,400,000 bf16
    // total 16,566,528 words = 66.3 MB

    hipMemsetAsync(ws, 0, (size_t)100064 * 4, stream); // counts+cursor+maxima+flag

    k_detect<<<1, 64, 0, stream>>>((const unsigned*)x, flag);

    k_setup<float, 1><<<1 + N_ET, 256, 0, stream>>>(W, emb, We, ae, Wt, he,
                                                    hemax, flag);
    k_setup<__hip_bfloat16, 0><<<1 + N_ET, 256, 0, stream>>>(W, emb, We, ae, Wt,
                                                             he, hemax, flag);

    k_proj<float, 1><<<1563, 256, 0, stream>>>(x, Wt, h, hl, hr, al, ar, flag);
    k_proj<__hip_bfloat16, 0><<<1563, 256, 0, stream>>>(x, Wt, h, hl, hr,
                                                        al, ar, flag);

    k_countaux<<<6250, 256, 0, stream>>>(edge, counts, hl, hr, hlmax, hrmax);
    k_scan<<<1, 256, 0, stream>>>(counts, offsets);
    k_build<<<6250, 256, 0, stream>>>(edge, offsets, cursor, hl, hr, he,
                                      hlmax, hrmax, hemax, rec);

    k_agg<float, 1><<<12500, 256, 0, stream>>>(rec, offsets, h, d_out, flag);
    k_agg<__hip_bfloat16, 0><<<12500, 256, 0, stream>>>(rec, offsets, h,
                                                        d_out, flag);
}

// Round 8
// 446.076 us; speedup vs baseline: 1.6346x; 1.0227x over previous
//
#include <hip/hip_runtime.h>
#include <hip/hip_bf16.h>
#include <hip/hip_fp16.h>

#define N_NODES 50000
#define N_EDGES 1600000
#define IN_H 256
#define NHEAD 4
#define EDGE_H 64
#define N_ET 8

// ---- ws layout (word offsets), total 10,166,528 words = 40.7 MB ----
// counts   int[50000]     @ 0          (zeroed)
// cursor   int[50000]     @ 50000      (zeroed)
// hlmax    u32[4]         @ 100000     (zeroed; enc_f32-encoded maxima)
// hrmax    u32[4]         @ 100004     (unused, kept for layout)
// hemax    u32[4]         @ 100008
// flag     int[1]         @ 100012
// hl       f32[200000]    @ 100064
// hr       f32[200000]    @ 300064
// offsets  int[50001]     @ 500064
// he       f32[32]        @ 550112
// Wt       bf16[32768]    @ 550144    (16384 words)
// rec      int[6400000]   @ 566528    (16B/edge: fp16 p0..3, s, e)
// h        bf16[6400000]  @ 6966528   (3200000 words)

typedef __attribute__((ext_vector_type(8))) short bf16x8v;
typedef __attribute__((ext_vector_type(4))) float f32x4;

__device__ __forceinline__ float ldT(const float* p) { return *p; }
__device__ __forceinline__ float ldT(const __hip_bfloat16* p) { return __bfloat162float(*p); }
__device__ __forceinline__ void stT(float* p, float v) { *p = v; }
__device__ __forceinline__ void stT(__hip_bfloat16* p, float v) { *p = __float2bfloat16(v); }

__device__ __forceinline__ short f2bs(float f) {
    __hip_bfloat16 b = __float2bfloat16(f);
    return (short)__builtin_bit_cast(unsigned short, b);
}
__device__ __forceinline__ float bs2f(short s) {
    return __uint_as_float(((unsigned)(unsigned short)s) << 16);
}

__device__ __forceinline__ unsigned enc_f32(float f) {
    unsigned u = __float_as_uint(f);
    return (u & 0x80000000u) ? ~u : (u | 0x80000000u);
}
__device__ __forceinline__ float dec_f32(unsigned u) {
    return __uint_as_float((u & 0x80000000u) ? (u & 0x7fffffffu) : ~u);
}
__device__ __forceinline__ float lrelu(float v) { return v > 0.f ? v : 0.2f * v; }

__device__ __forceinline__ unsigned pack_h2(float a, float b) {
    unsigned lo = (unsigned)__half_as_ushort(__float2half(a));
    unsigned hi = (unsigned)__half_as_ushort(__float2half(b));
    return lo | (hi << 16);
}
__device__ __forceinline__ float2 unpack_h2(int w) {
    __half2 h = __builtin_bit_cast(__half2, w);
    return __half22float2(h);
}

// dtype detector: fp32 N(0,1) words have exp-field in [64,160]; bf16-packed
// words don't. DEVICE-side sniffing only: in_sizes[] are ELEMENT counts
// (R5 post-mortem), so the host cannot distinguish dtypes.
__global__ void k_detect(const unsigned* __restrict__ xw, int* __restrict__ flag) {
    int lane = threadIdx.x;   // 64 threads
    int cnt = 0;
    for (int i = lane; i < 1024; i += 64) {
        unsigned e = (xw[i] >> 23) & 255u;
        if (e >= 64u && e <= 160u) cnt++;
    }
    for (int off = 32; off; off >>= 1) cnt += __shfl_xor(cnt, off);
    if (lane == 0) *flag = (cnt > 512) ? 1 : 0;   // 1 = fp32, 0 = bf16
}

// b0: W[256][128] -> Wt[128][256] bf16 (B^T layout for MFMA).
// b1..8: edge-type projection for type (b-1): he[ty][head] + hemax.
template<typename T, int EXPECT>
__global__ __launch_bounds__(256) void k_setup(
        const void* __restrict__ Wv, const void* __restrict__ embv,
        const void* __restrict__ Wev, const void* __restrict__ aev,
        __hip_bfloat16* __restrict__ Wt, float* __restrict__ h_e,
        unsigned* __restrict__ hemax, const int* __restrict__ flag) {
    if (*flag != EXPECT) return;
    const T* W   = (const T*)Wv;
    const T* emb = (const T*)embv;
    const T* We  = (const T*)Wev;
    const T* ae  = (const T*)aev;
    if (blockIdx.x == 0) {
        for (int i = threadIdx.x; i < 128 * 256; i += 256) {
            int c = i >> 8, k = i & 255;
            Wt[i] = __float2bfloat16(ldT(W + k * 128 + c));
        }
        return;
    }
    int ty = blockIdx.x - 1;
    int t = threadIdx.x, lane = t & 63;
    float acc = 0.f;
    for (int k = 0; k < EDGE_H; ++k)
        acc += ldT(emb + ty * EDGE_H + k) * ldT(We + k * 256 + t);
    float v = ldT(ae + t) * acc;
    for (int off = 32; off; off >>= 1) v += __shfl_xor(v, off);
    if (lane == 0) {
        h_e[ty * NHEAD + (t >> 6)] = v;
        atomicMax(&hemax[t >> 6], enc_f32(v));
    }
}

// h = x @ W via mfma_f32_16x16x32_bf16.
// 4 waves/block = 2 row-groups x 2 col-halves; 12500 waves (~6/SIMD).
// Prologue (AFTER flag guard -> runs exactly once): folded per-target edge
// counts, 1024 edges/block, fire-and-forget atomics hide under MFMA.
// Epilogue: hl/hr from in-register h (quarter-lane butterfly; col-half
// waves own disjoint heads -> plain stores). NO single-line maxima atomics
// here (R4: 100K atomicMax to one line serialized, +250us).
template<typename T, int EXPECT>
__global__ __launch_bounds__(256) void k_proj(const void* __restrict__ xv,
        const __hip_bfloat16* __restrict__ Wt, __hip_bfloat16* __restrict__ h,
        float* __restrict__ hl, float* __restrict__ hr,
        const void* __restrict__ alv, const void* __restrict__ arv,
        const int* __restrict__ edge, int* __restrict__ counts,
        const int* __restrict__ flag) {
    if (*flag != EXPECT) return;
    {   // folded k_count
        int base = blockIdx.x * 1024;
        int lim = min(base + 1024, N_EDGES);
        for (int i = base + threadIdx.x; i < lim; i += 256)
            atomicAdd(&counts[edge[N_EDGES + i]], 1);
    }
    const T* x  = (const T*)xv;
    const T* al = (const T*)alv;
    const T* ar = (const T*)arv;
    int wid = threadIdx.x >> 6, lane = threadIdx.x & 63;
    int rg = blockIdx.x * 2 + (wid >> 1);
    if (rg >= 3125) return;                 // no barriers below: safe early-exit
    int toff = (wid & 1) * 4;               // col-half: t-tiles toff..toff+3
    int r0 = rg * 16;
    int r = lane & 15;
    int kb = (lane >> 4) * 8;
    const T* xrow = x + (size_t)(r0 + r) * IN_H;
    f32x4 z = {0.f, 0.f, 0.f, 0.f};
    f32x4 acc[4];
#pragma unroll
    for (int t = 0; t < 4; ++t) acc[t] = z;
#pragma unroll
    for (int kk = 0; kk < 8; ++kk) {
        int k0 = kk * 32 + kb;
        bf16x8v a;
        if constexpr (sizeof(T) == 4) {
            float4 lo = *(const float4*)(xrow + k0);
            float4 hi = *(const float4*)(xrow + k0 + 4);
            a[0] = f2bs(lo.x); a[1] = f2bs(lo.y); a[2] = f2bs(lo.z); a[3] = f2bs(lo.w);
            a[4] = f2bs(hi.x); a[5] = f2bs(hi.y); a[6] = f2bs(hi.z); a[7] = f2bs(hi.w);
        } else {
            a = *(const bf16x8v*)(xrow + k0);
        }
#pragma unroll
        for (int t = 0; t < 4; ++t) {
            bf16x8v b = *(const bf16x8v*)(Wt + ((toff + t) * 16 + r) * 256 + k0);
            acc[t] = __builtin_amdgcn_mfma_f32_16x16x32_bf16(a, b, acc[t], 0, 0, 0);
        }
    }
    // epilogue: store h, accumulate hl/hr partials
    float alc[4], arc[4];
#pragma unroll
    for (int t = 0; t < 4; ++t) {
        alc[t] = ldT(al + (toff + t) * 16 + r);
        arc[t] = ldT(ar + (toff + t) * 16 + r);
    }
    int ob = (lane >> 4) * 4;               // this quarter's row offset
    float pl[2][4] = {{0,0,0,0},{0,0,0,0}}, pr[2][4] = {{0,0,0,0},{0,0,0,0}};
#pragma unroll
    for (int t = 0; t < 4; ++t) {
        int col = (toff + t) * 16 + r;
#pragma unroll
        for (int g = 0; g < 4; ++g) {
            float v = acc[t][g];
            if (v != v) v = 0.f;            // reference: where(isnan(h), 0)
            h[(size_t)(r0 + ob + g) * 128 + col] = __float2bfloat16(v);
            pl[t >> 1][g] += alc[t] * v;
            pr[t >> 1][g] += arc[t] * v;
        }
    }
#pragma unroll
    for (int hh = 0; hh < 2; ++hh)
#pragma unroll
        for (int g = 0; g < 4; ++g) {
            float vl = pl[hh][g], vr = pr[hh][g];
#pragma unroll
            for (int off = 8; off; off >>= 1) {
                vl += __shfl_xor(vl, off);
                vr += __shfl_xor(vr, off);
            }
            if (r == 0) {
                int node = r0 + ob + g;
                hl[node * 4 + (toff >> 1) + hh] = vl;
                hr[node * 4 + (toff >> 1) + hh] = vr;
            }
        }
}

// hl per-head maxima, 128 blocks (1024 total atomicMax — measured-safe).
// (hr maxima no longer needed: k_build uses per-target hr[t] directly.)
__global__ __launch_bounds__(256) void k_maxred(
        const float* __restrict__ hl, unsigned* __restrict__ hlmax) {
    const float NEG = -3.4e38f;
    float4 ml = {NEG, NEG, NEG, NEG};
    for (int n = blockIdx.x * 256 + threadIdx.x; n < N_NODES; n += 128 * 256) {
        float4 a = *(const float4*)(hl + n * 4);
        ml.x = fmaxf(ml.x, a.x); ml.y = fmaxf(ml.y, a.y);
        ml.z = fmaxf(ml.z, a.z); ml.w = fmaxf(ml.w, a.w);
    }
#pragma unroll
    for (int off = 32; off; off >>= 1) {
        ml.x = fmaxf(ml.x, __shfl_xor(ml.x, off));
        ml.y = fmaxf(ml.y, __shfl_xor(ml.y, off));
        ml.z = fmaxf(ml.z, __shfl_xor(ml.z, off));
        ml.w = fmaxf(ml.w, __shfl_xor(ml.w, off));
    }
    if ((threadIdx.x & 63) == 0) {
        atomicMax(&hlmax[0], enc_f32(ml.x)); atomicMax(&hlmax[1], enc_f32(ml.y));
        atomicMax(&hlmax[2], enc_f32(ml.z)); atomicMax(&hlmax[3], enc_f32(ml.w));
    }
}

// exclusive scan of counts -> offsets, 1024 threads, int4 both passes.
__global__ __launch_bounds__(1024) void k_scan(
        const int* __restrict__ counts, int* __restrict__ offsets) {
    __shared__ int psum[1024];
    int t = threadIdx.x;
    const int CHUNK = 52;                   // 13 int4 per thread, 962 active
    int start = t * CHUNK;
    int end = min(start + CHUNK, N_NODES);
    int s = 0;
    for (int i = start; i < end; i += 4) {
        int4 c = *(const int4*)(counts + i);
        s += c.x + c.y + c.z + c.w;
    }
    psum[t] = s;
    __syncthreads();
    for (int off = 1; off < 1024; off <<= 1) {
        int v = (t >= off) ? psum[t - off] : 0;
        __syncthreads();
        psum[t] += v;
        __syncthreads();
    }
    int run = (t == 0) ? 0 : psum[t - 1];
    for (int i = start; i < end; i += 4) {
        int4 c = *(const int4*)(counts + i);
        int4 o;
        o.x = run; o.y = run + c.x; o.z = o.y + c.y; o.w = o.z + c.z;
        *(int4*)(offsets + i) = o;
        run = o.w + c.w;
    }
    if (start < N_NODES && end == N_NODES) offsets[N_NODES] = run;
}

// CSR build: per edge one 16B record {fp16 p0..p3, s, e}.
// PER-TARGET-NODE shift (R7 post-mortem): M_t,h = lrelu(hlmax_h + hr[t][h]
// + hemax_h). Valid upper bound (lrelu monotone) => p <= 1; shift is
// constant within each (target,head) softmax group => exact math. Each
// group's dominant p is now >= exp(-(local slack)) — well inside fp16
// normal range, unlike R7's global-M which pushed whole groups subnormal.
__global__ __launch_bounds__(256) void k_build(
        const int* __restrict__ edge, const int* __restrict__ offsets,
        int* __restrict__ cursor,
        const float* __restrict__ hl, const float* __restrict__ hr,
        const float* __restrict__ he,
        const unsigned* __restrict__ hlmax, const unsigned* __restrict__ hemax,
        int* __restrict__ rec) {
    float G0 = dec_f32(hlmax[0]) + dec_f32(hemax[0]);
    float G1 = dec_f32(hlmax[1]) + dec_f32(hemax[1]);
    float G2 = dec_f32(hlmax[2]) + dec_f32(hemax[2]);
    float G3 = dec_f32(hlmax[3]) + dec_f32(hemax[3]);
    int e = blockIdx.x * 256 + threadIdx.x;   // 6250*256 == N_EDGES exactly
    int s = edge[e], t = edge[N_EDGES + e], ty = edge[2 * N_EDGES + e];
    int pos = offsets[t] + atomicAdd(&cursor[t], 1);
    float4 a = *(const float4*)(hl + s * 4);
    float4 b = *(const float4*)(hr + t * 4);
    float4 c = *(const float4*)(he + ty * 4);
    float p0 = __expf(lrelu(a.x + b.x + c.x) - lrelu(G0 + b.x));
    float p1 = __expf(lrelu(a.y + b.y + c.y) - lrelu(G1 + b.y));
    float p2 = __expf(lrelu(a.z + b.z + c.z) - lrelu(G2 + b.z));
    float p3 = __expf(lrelu(a.w + b.w + c.w) - lrelu(G3 + b.w));
    int4 w;
    w.x = (int)pack_h2(p0, p1);
    w.y = (int)pack_h2(p2, p3);
    w.z = s;
    w.w = e;
    *(int4*)(rec + (size_t)pos * 4) = w;
}

// one wave per node. pass1: lane-parallel denom (dense 16B/lane loads).
// pass2: 4 edges/iter — quarter-wave owns an edge, 16 lanes own 8 dims each
// (16B h load), cross-quarter shfl reduce at end. Zero transcendentals.
template<typename OUTT, int EXPECT>
__global__ __launch_bounds__(256) void k_agg(
        const int* __restrict__ rec, const int* __restrict__ offsets,
        const __hip_bfloat16* __restrict__ h, void* __restrict__ outv,
        const int* __restrict__ flag) {
    if (*flag != EXPECT) return;
    OUTT* out = (OUTT*)outv;
    int node = (blockIdx.x << 2) + (threadIdx.x >> 6);
    if (node >= N_NODES) return;
    int lane = threadIdx.x & 63;
    int beg = offsets[node], end = offsets[node + 1];

    // pass 1: denominators
    float d0 = 0.f, d1 = 0.f, d2 = 0.f, d3 = 0.f;
    for (int j = beg + lane; j < end; j += 64) {
        int2 w = *(const int2*)(rec + (size_t)j * 4);
        float2 f01 = unpack_h2(w.x);
        float2 f23 = unpack_h2(w.y);
        d0 += f01.x; d1 += f01.y; d2 += f23.x; d3 += f23.y;
    }
#pragma unroll
    for (int off = 32; off; off >>= 1) {
        d0 += __shfl_xor(d0, off); d1 += __shfl_xor(d1, off);
        d2 += __shfl_xor(d2, off); d3 += __shfl_xor(d3, off);
    }
    float inv0 = 1.f / (d0 + 1e-16f), inv1 = 1.f / (d1 + 1e-16f);
    float inv2 = 1.f / (d2 + 1e-16f), inv3 = 1.f / (d3 + 1e-16f);

    int sub = lane >> 4;          // edge slot within group of 4
    int l16 = lane & 15;          // dim group: flat dims l16*8 .. +8
    int hd  = l16 >> 2;           // head of my dims
    float invd = hd == 0 ? inv0 : hd == 1 ? inv1 : hd == 2 ? inv2 : inv3;
    float inva = l16 == 0 ? inv0 : l16 == 1 ? inv1 : l16 == 2 ? inv2 : inv3;
    OUTT* attn_out = out + (size_t)N_NODES * 128;

    float acc[8] = {0.f, 0.f, 0.f, 0.f, 0.f, 0.f, 0.f, 0.f};
    for (int jg = beg; jg < end; jg += 4) {
        int j = jg + sub;
        bool valid = j < end;
        int jc = valid ? j : end - 1;
        int4 w = *(const int4*)(rec + (size_t)jc * 4);
        float2 f01 = unpack_h2(w.x);
        float2 f23 = unpack_h2(w.y);
        int s = w.z;
        if (valid && l16 < 4) {    // attn output: lanes 0..3 of each quarter
            float ph = l16 == 0 ? f01.x : l16 == 1 ? f01.y : l16 == 2 ? f23.x : f23.y;
            stT(&attn_out[(size_t)w.w * 4 + l16], ph * inva);
        }
        float phd = hd == 0 ? f01.x : hd == 1 ? f01.y : hd == 2 ? f23.x : f23.y;
        float wgt = valid ? phd * invd : 0.f;
        bf16x8v hv = *(const bf16x8v*)(h + (size_t)s * 128 + l16 * 8);
#pragma unroll
        for (int i = 0; i < 8; ++i) acc[i] += bs2f(hv[i]) * wgt;
    }
#pragma unroll
    for (int i = 0; i < 8; ++i) {
        acc[i] += __shfl_xor(acc[i], 16);
        acc[i] += __shfl_xor(acc[i], 32);
    }
    if (sub == 0) {
#pragma unroll
        for (int i = 0; i < 8; ++i)
            stT(&out[(size_t)node * 128 + l16 * 8 + i], acc[i]);
    }
}

extern "C" void kernel_launch(void* const* d_in, const int* in_sizes, int n_in,
                              void* d_out, int out_size, void* d_ws, size_t ws_size,
                              hipStream_t stream) {
    const int* edge = (const int*)d_in[0];
    const void* x   = d_in[1];
    const void* emb = d_in[2];
    const void* W   = d_in[3];
    const void* We  = d_in[4];
    const void* al  = d_in[5];
    const void* ar  = d_in[6];
    const void* ae  = d_in[7];

    float* ws = (float*)d_ws;
    int* counts     = (int*)ws;                        // 50000
    int* cursor     = counts + 50000;                  // 50000
    unsigned* hlmax = (unsigned*)(counts + 100000);    // 4
    unsigned* hemax = hlmax + 8;                       // 4 (slot 100008)
    int* flag       = counts + 100012;                 // 1
    float* hl       = ws + 100064;                     // 200000
    float* hr       = ws + 300064;                     // 200000
    int* offsets    = (int*)ws + 500064;               // 50001
    float* he       = ws + 550112;                     // 32
    __hip_bfloat16* Wt = (__hip_bfloat16*)(ws + 550144);   // 32768 bf16
    int* rec        = (int*)ws + 566528;               // 6,400,000 (16B/edge)
    __hip_bfloat16* h = (__hip_bfloat16*)(ws + 6966528);   // 6,400,000 bf16
    // total 10,166,528 words = 40.7 MB

    hipMemsetAsync(ws, 0, (size_t)100064 * 4, stream); // counts+cursor+maxima+flag

    k_detect<<<1, 64, 0, stream>>>((const unsigned*)x, flag);

    k_setup<float, 1><<<1 + N_ET, 256, 0, stream>>>(W, emb, We, ae, Wt, he,
                                                    hemax, flag);
    k_setup<__hip_bfloat16, 0><<<1 + N_ET, 256, 0, stream>>>(W, emb, We, ae, Wt,
                                                             he, hemax, flag);

    k_proj<float, 1><<<1563, 256, 0, stream>>>(x, Wt, h, hl, hr, al, ar,
                                               edge, counts, flag);
    k_proj<__hip_bfloat16, 0><<<1563, 256, 0, stream>>>(x, Wt, h, hl, hr,
                                                        al, ar, edge, counts, flag);

    k_maxred<<<128, 256, 0, stream>>>(hl, hlmax);
    k_scan<<<1, 1024, 0, stream>>>(counts, offsets);
    k_build<<<6250, 256, 0, stream>>>(edge, offsets, cursor, hl, hr, he,
                                      hlmax, hemax, rec);

    k_agg<float, 1><<<12500, 256, 0, stream>>>(rec, offsets, h, d_out, flag);
    k_agg<__hip_bfloat16, 0><<<12500, 256, 0, stream>>>(rec, offsets, h,
                                                        d_out, flag);
}